// Round 10
// baseline (396.927 us; speedup 1.0000x reference)
//
#include <hip/hip_runtime.h>

#define N_PTS 20000
#define DIMS  128
#define A_CNT 1024
#define KNEG  10
#define NCHUNK_PAD 2560         // minbuf row stride in u16 (16B-aligned rows)
#define NCHUNK_REAL 2500        // 20000/8 real chunks
#define BIGV  1e18f
#define WCHUNK_CAP 512          // per-anchor candidate-chunk cap (E~120)
#define QCAP  393216            // global chunk-queue cap (E~250k)
#define SURV_CAP 320            // per-anchor survivor cap (E~60)

// v_sad_u8: d = c + sum |a.byte[i]-b.byte[i]| (4 dims per VALU op)
__device__ __forceinline__ unsigned int sad_u8(unsigned int a, unsigned int b, unsigned int c) {
#if __has_builtin(__builtin_amdgcn_sad_u8)
    return __builtin_amdgcn_sad_u8(a, b, c);
#else
    unsigned int d;
    asm("v_sad_u8 %0, %1, %2, %3" : "=v"(d) : "v"(a), "v"(b), "v"(c));
    return d;
#endif
}

// DPP cross-lane (VALU pipe). ROUND-9 BUG: row_ror:4 is dst i <- src (i-4)%16,
// which paired quad0 with quad3 (adjacent-chunk mixing). Correct 8-group
// pairing is row_half_mirror: lane i <- (i&~7)|(7-(i&7)) — always the OTHER
// quad of the SAME 8-group. row_mirror pairs the two 8-groups of a 16-row.
#define DPP_XOR1  0xB1   // quad_perm [1,0,3,2]
#define DPP_XOR2  0x4E   // quad_perm [2,3,0,1]
#define DPP_HMIRR 0x141  // row_half_mirror
#define DPP_MIRR  0x140  // row_mirror
template <int CTRL>
__device__ __forceinline__ int dpp_i(int v) {
    return __builtin_amdgcn_update_dpp(v, v, CTRL, 0xF, 0xF, false);
}
// all lanes end with min/sum of their 8-lane group
__device__ __forceinline__ unsigned int grp8_min(unsigned int v) {
    v = min(v, (unsigned int)dpp_i<DPP_XOR1>((int)v));
    v = min(v, (unsigned int)dpp_i<DPP_XOR2>((int)v));
    v = min(v, (unsigned int)dpp_i<DPP_HMIRR>((int)v));
    return v;
}
__device__ __forceinline__ int grp8_sum(int v) {
    v += dpp_i<DPP_XOR1>(v);
    v += dpp_i<DPP_XOR2>(v);
    v += dpp_i<DPP_HMIRR>(v);
    return v;
}
__device__ __forceinline__ float grp8_sum_f(float v) {
    v += __int_as_float(dpp_i<DPP_XOR1>(__float_as_int(v)));
    v += __int_as_float(dpp_i<DPP_XOR2>(__float_as_int(v)));
    v += __int_as_float(dpp_i<DPP_HMIRR>(__float_as_int(v)));
    return v;
}
__device__ __forceinline__ int wave_sum_i(int v) {
    v = grp8_sum(v);
    v += dpp_i<DPP_MIRR>(v);   // every lane: 16-row sum
    return __builtin_amdgcn_readlane(v, 0) + __builtin_amdgcn_readlane(v, 16)
         + __builtin_amdgcn_readlane(v, 32) + __builtin_amdgcn_readlane(v, 48);
}
__device__ __forceinline__ float wave_sum_f(float v) {
    v = grp8_sum_f(v);
    v += __int_as_float(dpp_i<DPP_MIRR>(__float_as_int(v)));
    return __int_as_float(__builtin_amdgcn_readlane(__float_as_int(v), 0))
         + __int_as_float(__builtin_amdgcn_readlane(__float_as_int(v), 16))
         + __int_as_float(__builtin_amdgcn_readlane(__float_as_int(v), 32))
         + __int_as_float(__builtin_amdgcn_readlane(__float_as_int(v), 48));
}

__device__ __forceinline__ void insert10f(float (&t)[10], float v) {
    if (v < t[9]) {
#pragma unroll
        for (int i = 9; i >= 1; --i) t[i] = fminf(t[i], fmaxf(t[i - 1], v));
        t[0] = fminf(t[0], v);
    }
}
__device__ __forceinline__ void mergeTop10f(float (&t)[10]) {
    for (int s = 1; s < 64; s <<= 1) {
        float o[10];
#pragma unroll
        for (int k = 0; k < 10; ++k) o[k] = __shfl_xor(t[k], s, 64);
#pragma unroll
        for (int k = 0; k < 10; ++k) insert10f(t, o[k]);
    }
}

// ---------------------------------------------------------------------------
__global__ void absmax_kernel(const float* __restrict__ a, const float* __restrict__ b,
                              unsigned int* __restrict__ amax) {
    const int n4 = N_PTS * DIMS / 4;
    const int stride = gridDim.x * blockDim.x;
    float m = 0.f;
    for (int i = blockIdx.x * blockDim.x + threadIdx.x; i < 2 * n4; i += stride) {
        const float4 v = (i < n4) ? ((const float4*)a)[i] : ((const float4*)b)[i - n4];
        m = fmaxf(m, fmaxf(fmaxf(fabsf(v.x), fabsf(v.y)), fmaxf(fabsf(v.z), fabsf(v.w))));
    }
#pragma unroll
    for (int s = 1; s < 64; s <<= 1) m = fmaxf(m, __shfl_xor(m, s, 64));
    if ((threadIdx.x & 63) == 0) atomicMax(amax, __float_as_uint(m));
}

// ---------------------------------------------------------------------------
// quantize q = rint(127*v/M + 127) in [0,254]; per-row residual sum
// R = sum_d |q_d - (s*v_d+127)| + 1.0 margin, and global Rmax.
// 8 consecutive lanes per row -> grp8_sum_f (fixed pairing).
// ---------------------------------------------------------------------------
__global__ void quantR_kernel(const float* __restrict__ src, unsigned int* __restrict__ dst,
                              float* __restrict__ Rrow, const unsigned int* __restrict__ amaxBits,
                              unsigned int* __restrict__ rmaxBits) {
    const int g = blockIdx.x * 256 + threadIdx.x;
    const int row = g >> 3;
    const int sub = g & 7;
    if (row >= N_PTS) return;
    const float M = __uint_as_float(*amaxBits);
    const float s = 127.0f / M;
    const float4* s4 = (const float4*)(src + (size_t)row * DIMS + sub * 16);
    unsigned int* d = dst + (size_t)row * 32 + sub * 4;
    float rs = 0.f;
#pragma unroll
    for (int m = 0; m < 4; ++m) {
        const float4 v = s4[m];
        const float f0 = v.x * s + 127.0f, f1 = v.y * s + 127.0f;
        const float f2 = v.z * s + 127.0f, f3 = v.w * s + 127.0f;
        const float q0 = rintf(f0), q1 = rintf(f1), q2 = rintf(f2), q3 = rintf(f3);
        rs += fabsf(q0 - f0) + fabsf(q1 - f1) + fabsf(q2 - f2) + fabsf(q3 - f3);
        d[m] = (unsigned int)q0 | ((unsigned int)q1 << 8) |
               ((unsigned int)q2 << 16) | ((unsigned int)q3 << 24);
    }
    rs = grp8_sum_f(rs);
    if (sub == 0) {
        const float R = rs + 1.0f;
        Rrow[row] = R;
        atomicMax(rmaxBits, __float_as_uint(R));
    }
}

// ---------------------------------------------------------------------------
// dist_sad4: block = 256 pts x 128 anchors. P row held in 32 VGPRs
// (__launch_bounds__(256,4) -> 128-reg budget; default bound made the
// compiler RE-LOAD P per anchor: VGPR=20, 80us). A rows stream via scalar
// pipe (readfirstlane -> s_load, SGPR srcs). Chunk-min via corrected DPP.
// ---------------------------------------------------------------------------
__global__ __launch_bounds__(256, 4)
void dist_sad4(const unsigned int* __restrict__ q1, const unsigned int* __restrict__ q2,
               const int* __restrict__ anchor1, const int* __restrict__ anchor2,
               unsigned short* __restrict__ minOut) {
    const int pb   = blockIdx.x;          // 0..78
    const int ag   = blockIdx.y;          // 0..7
    const int side = blockIdx.z;          // 0..1

    const unsigned int* aData = side ? q2 : q1;
    const unsigned int* pData = side ? q1 : q2;
    const int* aIdx = side ? anchor2 : anchor1;

    const int tid  = threadIdx.x;
    const int lane = tid & 63;
    const int pt   = pb * 256 + tid;
    const int ptc  = min(pt, N_PTS - 1);

    uint4 P0, P1, P2, P3, P4, P5, P6, P7;
    {
        const uint4* prow = (const uint4*)(pData + (size_t)ptc * 32);
        P0 = prow[0]; P1 = prow[1]; P2 = prow[2]; P3 = prow[3];
        P4 = prow[4]; P5 = prow[5]; P6 = prow[6]; P7 = prow[7];
    }

    const int chunk = pt >> 3;
    const bool doStore = ((lane & 7) == 0) && (pt < N_PTS);
    unsigned short* obase = minOut + (size_t)(side * A_CNT + ag * 128) * NCHUNK_PAD + chunk;

#pragma unroll 2
    for (int a = 0; a < 128; ++a) {
        const int arow = __builtin_amdgcn_readfirstlane(aIdx[ag * 128 + a]);
        const uint4* a4 = (const uint4*)(aData + (size_t)arow * 32);
        unsigned int s = 0u;
#define SADQ(A, P) { const uint4 A_ = (A); \
        s = sad_u8(A_.x, (P).x, s); s = sad_u8(A_.y, (P).y, s); \
        s = sad_u8(A_.z, (P).z, s); s = sad_u8(A_.w, (P).w, s); }
        SADQ(a4[0], P0) SADQ(a4[1], P1) SADQ(a4[2], P2) SADQ(a4[3], P3)
        SADQ(a4[4], P4) SADQ(a4[5], P5) SADQ(a4[6], P6) SADQ(a4[7], P7)
#undef SADQ
        const unsigned int mn = grp8_min(s);
        if (doStore) obase[(size_t)a * NCHUNK_PAD] = (unsigned short)mn;
    }
}

// ---------------------------------------------------------------------------
// select1: ONE WAVE per (side,anchor), zero barriers. 2560 chunk-mins loaded
// as 5 packed uint4/lane; PAD SLOTS (chunk >= 2500) SANITIZED to 0xFFFF in
// registers (no assumption about ws poison). m10ub by 11-iter binary search
// (granularity 16, DPP wave-sums). Candidates ballot-compacted; ONE global
// atomicAdd per wave reserves anchor-contiguous queue space.
// ---------------------------------------------------------------------------
__global__ __launch_bounds__(256)
void select1(const unsigned short* __restrict__ minIn,
             const int* __restrict__ anchor1, const int* __restrict__ anchor2,
             const float* __restrict__ R1, const float* __restrict__ R2,
             const unsigned int* __restrict__ rmaxBits,
             float* __restrict__ thrPt, unsigned int* __restrict__ queue,
             unsigned int* __restrict__ qCount) {
    __shared__ unsigned int cList[4][WCHUNK_CAP];
    const int tid = threadIdx.x;
    const int lane = tid & 63;
    const int wv = tid >> 6;
    const int sa = blockIdx.x * 4 + wv;    // 0..2047
    const int side = sa >> 10;
    const int ai = sa & 1023;
    const int* aIdx = side ? anchor2 : anchor1;
    const float* Ranc = side ? R2 : R1;

    const uint4* mrow = (const uint4*)(minIn + (size_t)sa * NCHUNK_PAD);
    uint4 w[5];
#pragma unroll
    for (int j = 0; j < 5; ++j) {
        w[j] = mrow[lane + 64 * j];
        // sanitize pad chunks (id >= NCHUNK_REAL) -> 0xFFFF per u16
        const int base = (lane + 64 * j) * 8;
        unsigned int* pw = (unsigned int*)&w[j];
#pragma unroll
        for (int m = 0; m < 4; ++m) {
            if (base + m * 2     >= NCHUNK_REAL) pw[m] |= 0x0000FFFFu;
            if (base + m * 2 + 1 >= NCHUNK_REAL) pw[m] |= 0xFFFF0000u;
        }
    }

    // binary search for smallest T (granularity 16) with count(<= T) >= 10
    int lo = 0, hi = 32768;
#pragma unroll 1
    while (hi - lo > 16) {
        const int mid = (lo + hi) >> 1;
        int c = 0;
#pragma unroll
        for (int j = 0; j < 5; ++j) {
            const unsigned int* pw = (const unsigned int*)&w[j];
#pragma unroll
            for (int m = 0; m < 4; ++m) {
                c += ((int)(pw[m] & 0xFFFFu) <= mid);
                c += ((int)(pw[m] >> 16) <= mid);
            }
        }
        if (wave_sum_i(c) >= 10) hi = mid; else lo = mid;
    }

    const int arow = __builtin_amdgcn_readfirstlane(aIdx[ai]);
    const float Ra = Ranc[arow];
    const float Rm = __uint_as_float(*rmaxBits);
    const int thrCi = (int)((float)hi + 2.f * Ra + 2.f * Rm + 4.f);  // < 0xFFFF
    if (lane == 0) thrPt[sa] = (float)hi + 2.f * Ra + Rm + 4.f;

    // ballot-compact candidates into the per-wave LDS list
    const unsigned long long lmask = (lane == 63) ? ~0ull >> 1 : (1ull << lane) - 1;
    unsigned int S = 0;
#pragma unroll
    for (int j = 0; j < 5; ++j) {
        const unsigned int* pw = (const unsigned int*)&w[j];
#pragma unroll
        for (int m = 0; m < 4; ++m) {
#pragma unroll
            for (int h = 0; h < 2; ++h) {
                const int v16 = h ? (int)(pw[m] >> 16) : (int)(pw[m] & 0xFFFFu);
                const bool pred = v16 <= thrCi;
                const unsigned long long mask = __ballot(pred);
                if (pred) {
                    const unsigned int slot = S + (unsigned int)__popcll(mask & lmask);
                    if (slot < WCHUNK_CAP)
                        cList[wv][slot] = (unsigned int)((lane + 64 * j) * 8 + m * 2 + h);
                }
                S += (unsigned int)__popcll(mask);
            }
        }
    }
    S = min(S, (unsigned int)WCHUNK_CAP);

    unsigned int base = 0;
    if (lane == 0) base = atomicAdd(qCount, S);
    base = (unsigned int)__builtin_amdgcn_readfirstlane((int)base);
    const unsigned int tag = (unsigned int)sa << 12;
    for (unsigned int i = lane; i < S; i += 64) {
        const unsigned int q = base + i;
        if (q < QCAP) queue[q] = tag | cList[wv][i];
    }
}

// ---------------------------------------------------------------------------
// select2: one wave per contiguous run of queue entries. u8 SAD filter
// (corrected grp8_sum); survivors get the exact fp32 L1 immediately (anchor
// row L1-cached across same-anchor runs) and the DISTANCE is appended.
// Superset proof: d_int(p) <= m10ub + 2Ra + Rmax + Rp for true top-10 p.
// ---------------------------------------------------------------------------
__global__ __launch_bounds__(256)
void select2(const float* __restrict__ out1, const float* __restrict__ out2,
             const unsigned int* __restrict__ q1, const unsigned int* __restrict__ q2,
             const int* __restrict__ anchor1, const int* __restrict__ anchor2,
             const float* __restrict__ R1, const float* __restrict__ R2,
             const float* __restrict__ thrPt, const unsigned int* __restrict__ queue,
             const unsigned int* __restrict__ qCount,
             float* __restrict__ survDist, unsigned int* __restrict__ survCnt) {
    const int tid = threadIdx.x;
    const int lane = tid & 63;
    const unsigned int wid = (blockIdx.x * 256 + tid) >> 6;
    const unsigned int nw = gridDim.x * 4;
    const unsigned int qn = min(*qCount, (unsigned int)QCAP);
    const unsigned int per = (qn + nw - 1) / nw;
    const unsigned int e0 = wid * per;
    const unsigned int e1 = min(qn, e0 + per);

    const int psub = lane >> 3;
    const int seg  = lane & 7;

    for (unsigned int e = e0; e < e1; ++e) {
        const unsigned int ent = queue[e];
        const int sa = (int)(ent >> 12);
        const int chunk = (int)(ent & 0xFFFu);
        const int side = sa >> 10;
        const int ai = sa & 1023;
        const int* aIdx = side ? anchor2 : anchor1;
        const unsigned int* aQ = side ? q2 : q1;
        const unsigned int* pQ = side ? q1 : q2;
        const float* aF = side ? out2 : out1;
        const float* pF = side ? out1 : out2;
        const float* Rp = side ? R1 : R2;       // residuals of the P side

        const int arow = __builtin_amdgcn_readfirstlane(aIdx[ai]);
        const int pt = chunk * 8 + psub;
        const uint4 qa = ((const uint4*)(aQ + (size_t)arow * 32))[seg];
        const uint4 qp = ((const uint4*)(pQ + (size_t)pt * 32))[seg];
        unsigned int d = sad_u8(qa.x, qp.x, 0u);
        d = sad_u8(qa.y, qp.y, d);
        d = sad_u8(qa.z, qp.z, d);
        d = sad_u8(qa.w, qp.w, d);
        const int di = grp8_sum((int)d);
        const bool pass = (seg == 0) && ((float)di <= thrPt[sa] + Rp[pt]);
        unsigned long long mask = __ballot(pass);

        if (mask) {
            const float2 av = ((const float2*)(aF + (size_t)arow * DIMS))[lane];
            do {
                const int src = __ffsll(mask) - 1;
                mask &= mask - 1;
                const int ptb = chunk * 8 + (src >> 3);
                const float2 pv = ((const float2*)(pF + (size_t)ptb * DIMS))[lane];
                const float tot = wave_sum_f(fabsf(av.x - pv.x) + fabsf(av.y - pv.y));
                if (lane == 0) {
                    const unsigned int pos = atomicAdd(&survCnt[sa], 1u);
                    if (pos < SURV_CAP) survDist[(size_t)sa * SURV_CAP + pos] = tot;
                }
            } while (mask);
        }
    }
}

// ---------------------------------------------------------------------------
// select3: one wave per (side, anchor): Dm + top-10 of survivor distances,
// one atomicAdd. >= 10 survivors guaranteed (true top-10 pass all filters).
// ---------------------------------------------------------------------------
__global__ __launch_bounds__(256)
void select3(const float* __restrict__ out1, const float* __restrict__ out2,
             const int* __restrict__ anchor1, const int* __restrict__ anchor2,
             const float* __restrict__ survDist, const unsigned int* __restrict__ survCnt,
             float* __restrict__ out) {
    const int tid = threadIdx.x;
    const int lane = tid & 63;
    const int sa = blockIdx.x * 4 + (tid >> 6);   // 0..2047
    const int ai = sa & 1023;

    const int r1 = anchor1[ai], r2 = anchor2[ai];
    const float2 x1 = ((const float2*)(out1 + (size_t)r1 * DIMS))[lane];
    const float2 x2 = ((const float2*)(out2 + (size_t)r2 * DIMS))[lane];
    const float dm = wave_sum_f(fabsf(x1.x - x2.x) + fabsf(x1.y - x2.y)) + 1.0f; // GAMMA

    const unsigned int n = min(survCnt[sa], (unsigned int)SURV_CAP);
    float t[10];
#pragma unroll
    for (int k = 0; k < 10; ++k) t[k] = BIGV;
    const float* dv = survDist + (size_t)sa * SURV_CAP;
    for (unsigned int i = lane; i < n; i += 64) insert10f(t, dv[i]);
    mergeTop10f(t);

    if (lane == 0) {
        float sum = 0.f;
#pragma unroll
        for (int k = 0; k < 10; ++k) sum += fmaxf(dm - t[k], 0.f);
        atomicAdd(out, sum * (1.0f / (A_CNT * KNEG)));
    }
}

extern "C" void kernel_launch(void* const* d_in, const int* in_sizes, int n_in,
                              void* d_out, int out_size, void* d_ws, size_t ws_size,
                              hipStream_t stream) {
    const float* out1    = (const float*)d_in[0];
    const float* out2    = (const float*)d_in[1];
    const int*   anchor1 = (const int*)d_in[2];
    const int*   anchor2 = (const int*)d_in[3];
    float* out = (float*)d_out;

    // ws layout (~19.9 MB)
    unsigned int* q1 = (unsigned int*)d_ws;                          // 640000 u32
    unsigned int* q2 = q1 + 640000;                                  // 640000 u32
    float* survDist = (float*)(q2 + 640000);                         // 2048*320 f32
    unsigned short* minbuf = (unsigned short*)(survDist + 2048 * SURV_CAP); // 2048*2560 u16
    float* R1 = (float*)(minbuf + (size_t)2048 * NCHUNK_PAD);        // 20000
    float* R2 = R1 + N_PTS;                                          // 20000
    float* thrPt = R2 + N_PTS;                                       // 2048
    unsigned int* queue = (unsigned int*)(thrPt + 2048);             // QCAP
    unsigned int* survCnt = queue + QCAP;                            // 2048
    unsigned int* qCnt = survCnt + 2048;                             // 1
    unsigned int* amax = qCnt + 1;                                   // 1
    unsigned int* rmax = amax + 1;                                   // 1

    hipMemsetAsync(out, 0, sizeof(float), stream);
    hipMemsetAsync(survCnt, 0, (2048 + 3) * sizeof(unsigned int), stream);

    hipLaunchKernelGGL(absmax_kernel, dim3(1024), dim3(256), 0, stream, out1, out2, amax);
    const int qblocks = (N_PTS * 8 + 255) / 256;
    hipLaunchKernelGGL(quantR_kernel, dim3(qblocks), dim3(256), 0, stream, out1, q1, R1, amax, rmax);
    hipLaunchKernelGGL(quantR_kernel, dim3(qblocks), dim3(256), 0, stream, out2, q2, R2, amax, rmax);

    hipLaunchKernelGGL(dist_sad4, dim3(79, 8, 2), dim3(256), 0, stream,
                       q1, q2, anchor1, anchor2, minbuf);
    hipLaunchKernelGGL(select1, dim3(512), dim3(256), 0, stream,
                       minbuf, anchor1, anchor2, R1, R2, rmax, thrPt, queue, qCnt);
    hipLaunchKernelGGL(select2, dim3(2048), dim3(256), 0, stream,
                       out1, out2, q1, q2, anchor1, anchor2, R1, R2,
                       thrPt, queue, qCnt, survDist, survCnt);
    hipLaunchKernelGGL(select3, dim3(512), dim3(256), 0, stream,
                       out1, out2, anchor1, anchor2, survDist, survCnt, out);
}